// Round 1
// 198.308 us; speedup vs baseline: 4.6089x; 4.6089x over previous
//
#include <hip/hip_runtime.h>
#include <math.h>

#define BB   64      // batch
#define TT   512     // time
#define NCH  7       // channels
#define SS   4       // scales
#define MM   100000  // memory entries
#define DD   64      // embed dim
#define PRED 96      // pred_len
#define NBLK 256     // k2 blocks per scale
#define KPB  391     // ceil(MM/NBLK)
#define KLS  68      // key LDS row stride (floats): 16B-aligned rows, banks spread

// ---------------- reductions ----------------
__device__ __forceinline__ float wsum(float v){
  v += __shfl_xor(v,32); v += __shfl_xor(v,16); v += __shfl_xor(v,8);
  v += __shfl_xor(v,4);  v += __shfl_xor(v,2);  v += __shfl_xor(v,1);
  return v;
}
__device__ __forceinline__ float wmaxall(float v){
  v = fmaxf(v,__shfl_xor(v,32)); v = fmaxf(v,__shfl_xor(v,16));
  v = fmaxf(v,__shfl_xor(v,8));  v = fmaxf(v,__shfl_xor(v,4));
  v = fmaxf(v,__shfl_xor(v,2));  v = fmaxf(v,__shfl_xor(v,1));
  return v;
}
__device__ __forceinline__ float wminall(float v){
  v = fminf(v,__shfl_xor(v,32)); v = fminf(v,__shfl_xor(v,16));
  v = fminf(v,__shfl_xor(v,8));  v = fminf(v,__shfl_xor(v,4));
  v = fminf(v,__shfl_xor(v,2));  v = fminf(v,__shfl_xor(v,1));
  return v;
}
__device__ __forceinline__ float bsum(float v, float* red, int wid, int lane){
  v = wsum(v);
  __syncthreads();
  if (lane==0) red[wid]=v;
  __syncthreads();
  return (red[0]+red[1])+(red[2]+red[3]);
}
__device__ __forceinline__ float bmax(float v, float* red, int wid, int lane){
  v = wmaxall(v);
  __syncthreads();
  if (lane==0) red[wid]=v;
  __syncthreads();
  return fmaxf(fmaxf(red[0],red[1]),fmaxf(red[2],red[3]));
}
__device__ __forceinline__ float bmin(float v, float* red, int wid, int lane){
  v = wminall(v);
  __syncthreads();
  if (lane==0) red[wid]=v;
  __syncthreads();
  return fminf(fminf(red[0],red[1]),fminf(red[2],red[3]));
}

__device__ __forceinline__ float log_marg(float n, float mean, float var,
                                          float pm, float pv, float nv){
  float post_var = 1.f/(1.f/pv + n/nv);
  float post_mean = post_var*(pm/pv + n*mean/nv);
  return -0.5f*n*logf(6.283185307179586f*nv)
       + 0.5f*logf(post_var/pv)
       - 0.5f*(n*var/nv + mean*mean*n/nv - post_mean*post_mean/post_var + pm*pm/pv);
}

// sorted-desc top5 insert on registers tv0..tv4 / ti0..ti4
#define TOP5_INSERT(v, ii) \
  if ((v) > tv4) { \
    if ((v) > tv0){ tv4=tv3;ti4=ti3;tv3=tv2;ti3=ti2;tv2=tv1;ti2=ti1;tv1=tv0;ti1=ti0;tv0=(v);ti0=(ii);} \
    else if ((v) > tv1){ tv4=tv3;ti4=ti3;tv3=tv2;ti3=ti2;tv2=tv1;ti2=ti1;tv1=(v);ti1=(ii);} \
    else if ((v) > tv2){ tv4=tv3;ti4=ti3;tv3=tv2;ti3=ti2;tv2=(v);ti2=(ii);} \
    else if ((v) > tv3){ tv4=tv3;ti4=ti3;tv3=(v);ti3=(ii);} \
    else { tv4=(v);ti4=(ii);} \
  }

// ---------------- kernel 1: stats + changepoint + mode + encodings ----------------
__global__ __launch_bounds__(256) void k1_setup(
    const float* __restrict__ x,
    const float* __restrict__ cls_w, const float* __restrict__ cls_b,
    const float* __restrict__ prior_mean, const float* __restrict__ prior_var,
    const float* __restrict__ noise_var,
    const float* __restrict__ enc_W, const float* __restrict__ enc_b,
    const float* __restrict__ ln_g, const float* __restrict__ ln_b,
    float* __restrict__ q_ws, int* __restrict__ mode_ws)
{
  __shared__ float xl[TT*NCH];
  __shared__ float xf[TT];
  __shared__ float s1[TT+1];
  __shared__ float s2[TT+1];
  __shared__ float bfl[TT-32];
  __shared__ float xd[TT];
  __shared__ float red[4];
  int b = blockIdx.x, t = threadIdx.x;
  int lane = t & 63, wid = t >> 6;

  for (int i=t; i<TT*NCH; i+=256) xl[i] = x[(size_t)b*TT*NCH + i];
  __syncthreads();
  for (int i=t; i<TT; i+=256){
    float s=0.f;
    #pragma unroll
    for (int n=0;n<NCH;n++) s += xl[i*NCH+n];
    xf[i] = s*(1.0f/NCH);
  }
  __syncthreads();

  // ---- classifier feats (per-channel stats, then mean over channels) ----
  float sum[NCH], ssq[NCH], mxa[NCH], mna[NCH];
  #pragma unroll
  for(int n=0;n<NCH;n++){ sum[n]=0.f; ssq[n]=0.f; mxa[n]=-INFINITY; mna[n]=INFINITY; }
  for (int i=t;i<TT;i+=256){
    #pragma unroll
    for(int n=0;n<NCH;n++){
      float v = xl[i*NCH+n];
      sum[n]+=v; ssq[n]+=v*v; mxa[n]=fmaxf(mxa[n],v); mna[n]=fminf(mna[n],v);
    }
  }
  float f_mean=0.f, f_std=0.f, f_max=0.f, f_min=0.f;
  #pragma unroll
  for(int n=0;n<NCH;n++){
    float sn  = bsum(sum[n], red, wid, lane);
    float qn  = bsum(ssq[n], red, wid, lane);
    float xn  = bmax(mxa[n], red, wid, lane);
    float mn2 = bmin(mna[n], red, wid, lane);
    float m = sn*(1.0f/TT);
    float var = (qn - (float)TT*m*m)*(1.0f/(TT-1));
    f_mean += m; f_std += sqrtf(fmaxf(var, 0.f)); f_max += xn; f_min += mn2;
  }
  f_mean *= (1.0f/NCH); f_std *= (1.0f/NCH); f_max *= (1.0f/NCH); f_min *= (1.0f/NCH);
  f_std = fmaxf(f_std, 1e-6f);
  float trend = 0.f;
  #pragma unroll
  for(int n=0;n<NCH;n++) trend += (xl[(TT-1)*NCH+n]-xl[n]);
  trend *= (1.0f/NCH);
  float z = f_mean*cls_w[0]+f_std*cls_w[1]+f_max*cls_w[2]+f_min*cls_w[3]+trend*cls_w[4]+cls_b[0];
  float extreme_prob = 1.f/(1.f+expf(-z));

  // ---- cumsums (serial, T=512) ----
  if (t==0){
    float a=0.f, c=0.f; s1[0]=0.f; s2[0]=0.f;
    for (int i=0;i<TT;i++){ float v=xf[i]; a+=v; c+=v*v; s1[i+1]=a; s2[i+1]=c; }
  }
  __syncthreads();

  // ---- Bayesian change point ----
  float pm = prior_mean[0];
  float pv = log1pf(expf(prior_var[0]));
  float nv = log1pf(expf(noise_var[0]));
  float sAll = s1[TT], qAll = s2[TT];
  float mw = sAll*(1.0f/TT);
  float vw = fmaxf((qAll - (float)TT*mw*mw)*(1.0f/(TT-1)), 1e-8f);
  float lmw = log_marg((float)TT, mw, vw, pm, pv, nv);
  for (int pp=16+t; pp<TT-16; pp+=256){
    float nl=(float)pp, nr=(float)(TT-pp);
    float ml=s1[pp]/nl;
    float vl=fmaxf((s2[pp]-nl*ml*ml)/(nl-1.f), 1e-8f);
    float sr=sAll-s1[pp], qr=qAll-s2[pp];
    float mr=sr/nr;
    float vr=fmaxf((qr-nr*mr*mr)/(nr-1.f), 1e-8f);
    bfl[pp-16] = log_marg(nl,ml,vl,pm,pv,nv)+log_marg(nr,mr,vr,pm,pv,nv)-lmw;
  }
  __syncthreads();
  float mv = -INFINITY;
  for (int i=t;i<TT-32;i+=256) mv = fmaxf(mv, bfl[i]);
  mv = bmax(mv, red, wid, lane);
  float se=0.f, sme=0.f;
  for (int i=t;i<TT-32;i+=256){
    float e = expf(bfl[i]-mv);
    se += e;
    if (i+16 > 409) sme += e;   // pos > int(512*0.8)=409
  }
  se  = bsum(se,  red, wid, lane);
  sme = bsum(sme, red, wid, lane);
  float near_end = (1.f/(1.f+expf(-mv))) * (sme/se);
  if (t==0) mode_ws[b] = (near_end>0.5f) ? 2 : ((extreme_prob>0.5f) ? 1 : 0);

  // ---- per-scale encodings ----
  for (int si=0; si<SS; si++){
    int ds = 1<<si, Td = TT>>si;
    __syncthreads();
    for (int i=t;i<Td;i+=256)
      xd[i] = (si==0) ? xf[i] : (s1[(i+1)*ds]-s1[i*ds])*(1.0f/(float)ds);
    __syncthreads();
    float s=0.f, qq=0.f, mxv=-INFINITY, mnv=INFINITY;
    for (int i=t;i<Td;i+=256){ float v=xd[i]; s+=v; qq+=v*v; mxv=fmaxf(mxv,v); mnv=fminf(mnv,v); }
    s   = bsum(s,  red, wid, lane);
    qq  = bsum(qq, red, wid, lane);
    mxv = bmax(mxv, red, wid, lane);
    mnv = bmin(mnv, red, wid, lane);
    float m  = s/(float)Td;
    float sd = fmaxf(sqrtf(fmaxf((qq-(float)Td*m*m)/((float)Td-1.f), 0.f)), 1e-6f);
    float tr = xd[Td-1]-xd[0];
    if (t < DD){
      float h = m*enc_W[0*DD+t] + sd*enc_W[1*DD+t] + mxv*enc_W[2*DD+t]
              + mnv*enc_W[3*DD+t] + tr*enc_W[4*DD+t] + enc_b[t];
      float mu  = wsum(h)*(1.0f/DD);
      float dv  = h-mu;
      float var = wsum(dv*dv)*(1.0f/DD);
      float hn  = dv*rsqrtf(var+1e-5f)*ln_g[t] + ln_b[t];
      float nrm2 = wsum(hn*hn);
      q_ws[(((size_t)si*BB)+b)*DD + t] = hn*rsqrtf(nrm2);
    }
  }
}

// ---------------- kernel 2: sims GEMV + per-block top5 ----------------
// Phase A restructure vs previous version: NO per-lane kr[64] array (it was
// spilling to scratch -> 1.13 GB of scratch writes/dispatch, VALUBusy 2%).
// lane = key, acc[16] (one per batch of the wave's slice), d-chunked by 8.
// q is staged once per block into LDS; q reads are wave-uniform (broadcast).
__global__ __launch_bounds__(256,3) void k2_sims(
    const float* __restrict__ keys, const int* __restrict__ labels,
    const float* __restrict__ q_ws, const int* __restrict__ mode_ws,
    float* __restrict__ cand_val, int* __restrict__ cand_idx)
{
  __shared__ float kl[64*KLS];     // staged key tile [key][dim], stride 68
  __shared__ float qls[64*DD];     // staged q for this scale [batch][dim]
  __shared__ float sims[64*65];    // [key][batch], stride 65 (2-way alias = free)
  __shared__ int   lab[64];
  int bid = blockIdx.x;
  int s   = bid / NBLK, blk = bid % NBLK;
  int t = threadIdx.x, lane = t & 63;
  int w = __builtin_amdgcn_readfirstlane(t >> 6);   // wave id, provably uniform
  int k0   = blk*KPB;
  int kend = min(MM, k0+KPB);
  int mode_l = mode_ws[lane];                        // lane = batch in phase B
  const float* qbase = q_ws + (size_t)s*BB*DD;

  // stage q once (16 KB, reused for all ~6 key tiles)
  for (int i=t; i<BB*DD/4; i+=256){
    float4 v = *(const float4*)(qbase + (size_t)i*4);
    *(float4*)(qls + i*4) = v;
  }
  // (first __syncthreads below covers this staging too)

  float tv0=-INFINITY,tv1=-INFINITY,tv2=-INFINITY,tv3=-INFINITY,tv4=-INFINITY;
  int   ti0=0,ti1=0,ti2=0,ti3=0,ti4=0;

  for (int c0=k0; c0<kend; c0+=64){
    int cn = min(64, kend-c0);
    // stage keys (coalesced float4 read, strided-row LDS write) + labels
    for (int i=t; i<cn*16; i+=256){
      float4 v = *(const float4*)(keys + (size_t)s*MM*DD + (size_t)c0*DD + (size_t)i*4);
      int key = i >> 4, dch = i & 15;
      *(float4*)(kl + key*KLS + dch*4) = v;
    }
    if (t < cn) lab[t] = labels[(size_t)s*MM + c0 + t];
    __syncthreads();

    // phase A: lane = key; 16 accumulators (wave's 16 batches); d-chunks of 8
    if (lane < cn){
      float acc[16];
      #pragma unroll
      for (int bi=0; bi<16; bi++) acc[bi]=0.f;
      const float* kp = kl + lane*KLS;
      const float* qp0 = qls + (w*16)*DD;
      #pragma unroll 2
      for (int dc=0; dc<DD; dc+=8){
        float4 ka = *(const float4*)(kp + dc);
        float4 kb = *(const float4*)(kp + dc + 4);
        #pragma unroll
        for (int bi=0; bi<16; bi++){
          const float* qp = qp0 + bi*DD + dc;
          float4 qa = *(const float4*)(qp);
          float4 qb = *(const float4*)(qp + 4);
          acc[bi] += ((ka.x*qa.x + ka.y*qa.y) + (ka.z*qa.z + ka.w*qa.w))
                   + ((kb.x*qb.x + kb.y*qb.y) + (kb.z*qb.z + kb.w*qb.w));
        }
      }
      #pragma unroll
      for (int bi=0; bi<16; bi++)
        sims[lane*65 + (w*16+bi)] = acc[bi];
    }
    __syncthreads();

    // phase B: lane = batch; each wave scans its 16-key slice
    int mlo = w*16, mhi = min(cn, w*16+16);
    for (int m=mlo; m<mhi; m++){
      int lb = lab[m];
      float v = sims[m*65+lane];
      bool allowed = (mode_l==0) | (lb==mode_l);
      if (allowed){
        int gidx = c0+m;
        TOP5_INSERT(v, gidx)
      }
    }
    __syncthreads();
  }

  // merge 4 wave-lists per batch -> per-block sorted top5
  float* mvp = sims;       // reuse
  int*   mip = (int*)kl;   // reuse
  int slot = (w*64+lane)*5;
  mvp[slot+0]=tv0; mvp[slot+1]=tv1; mvp[slot+2]=tv2; mvp[slot+3]=tv3; mvp[slot+4]=tv4;
  mip[slot+0]=ti0; mip[slot+1]=ti1; mip[slot+2]=ti2; mip[slot+3]=ti3; mip[slot+4]=ti4;
  __syncthreads();
  if (t < 64){
    float tv0=mvp[t*5+0], tv1=mvp[t*5+1], tv2=mvp[t*5+2], tv3=mvp[t*5+3], tv4=mvp[t*5+4];
    int   ti0=mip[t*5+0], ti1=mip[t*5+1], ti2=mip[t*5+2], ti3=mip[t*5+3], ti4=mip[t*5+4];
    #pragma unroll
    for (int ww=1; ww<4; ww++){
      #pragma unroll
      for (int j=0;j<5;j++){
        float v = mvp[(ww*64+t)*5+j]; int ii = mip[(ww*64+t)*5+j];
        TOP5_INSERT(v, ii)
      }
    }
    size_t o = (((size_t)s*NBLK + blk)*BB + t)*5;
    cand_val[o+0]=tv0; cand_val[o+1]=tv1; cand_val[o+2]=tv2; cand_val[o+3]=tv3; cand_val[o+4]=tv4;
    cand_idx[o+0]=ti0; cand_idx[o+1]=ti1; cand_idx[o+2]=ti2; cand_idx[o+3]=ti3; cand_idx[o+4]=ti4;
  }
}

// ---------------- kernel 3: merge candidates, softmax, gather values ----------------
__global__ __launch_bounds__(256) void k3_merge(
    const float* __restrict__ cand_val, const int* __restrict__ cand_idx,
    const float* __restrict__ values, const float* __restrict__ thresholds,
    float* __restrict__ top1_ws, float* __restrict__ retr_ws,
    float* __restrict__ out)
{
  __shared__ float lv[NBLK*5];
  __shared__ int   li[NBLK*5];
  __shared__ float wsm[5];
  __shared__ int   wix[5];
  int bid = blockIdx.x;
  int s = bid >> 6, b = bid & 63;
  int t = threadIdx.x;
  size_t o = (((size_t)s*NBLK + t)*BB + b)*5;
  float tv0=cand_val[o+0], tv1=cand_val[o+1], tv2=cand_val[o+2], tv3=cand_val[o+3], tv4=cand_val[o+4];
  int   ti0=cand_idx[o+0], ti1=cand_idx[o+1], ti2=cand_idx[o+2], ti3=cand_idx[o+3], ti4=cand_idx[o+4];
  lv[t*5+0]=tv0; lv[t*5+1]=tv1; lv[t*5+2]=tv2; lv[t*5+3]=tv3; lv[t*5+4]=tv4;
  li[t*5+0]=ti0; li[t*5+1]=ti1; li[t*5+2]=ti2; li[t*5+3]=ti3; li[t*5+4]=ti4;
  __syncthreads();
  for (int stride=128; stride>=1; stride>>=1){
    if (t < stride){
      int p = t+stride;
      #pragma unroll
      for (int j=0;j<5;j++){
        float v = lv[p*5+j]; int ii = li[p*5+j];
        TOP5_INSERT(v, ii)
      }
      lv[t*5+0]=tv0; lv[t*5+1]=tv1; lv[t*5+2]=tv2; lv[t*5+3]=tv3; lv[t*5+4]=tv4;
      li[t*5+0]=ti0; li[t*5+1]=ti1; li[t*5+2]=ti2; li[t*5+3]=ti3; li[t*5+4]=ti4;
    }
    __syncthreads();
  }
  if (t==0){
    float e1=expf(tv1-tv0), e2=expf(tv2-tv0), e3=expf(tv3-tv0), e4=expf(tv4-tv0);
    float inv = 1.f/(1.f+e1+e2+e3+e4);
    wsm[0]=inv; wsm[1]=e1*inv; wsm[2]=e2*inv; wsm[3]=e3*inv; wsm[4]=e4*inv;
    wix[0]=ti0; wix[1]=ti1; wix[2]=ti2; wix[3]=ti3; wix[4]=ti4;
    top1_ws[s*BB+b] = tv0;
    out[(size_t)BB*PRED*NCH + b*SS + s] = 1.f/(1.f+expf(-(tv0-thresholds[s])));
  }
  __syncthreads();
  if (t < PRED){
    float acc=0.f;
    #pragma unroll
    for (int j=0;j<5;j++)
      acc += wsm[j]*values[((size_t)s*MM + wix[j])*PRED + t];
    retr_ws[((size_t)s*BB + b)*PRED + t] = acc;
  }
}

// ---------------- kernel 4: cross-scale fuse + broadcast over channels ----------------
__global__ __launch_bounds__(128) void k4_fuse(
    const float* __restrict__ top1_ws, const float* __restrict__ retr_ws,
    float* __restrict__ out)
{
  int b = blockIdx.x, t = threadIdx.x;
  float t0=top1_ws[b], t1=top1_ws[BB+b], t2=top1_ws[2*BB+b], t3=top1_ws[3*BB+b];
  float mx = fmaxf(fmaxf(t0,t1),fmaxf(t2,t3));
  float e0=expf(t0-mx), e1=expf(t1-mx), e2=expf(t2-mx), e3=expf(t3-mx);
  float inv = 1.f/(e0+e1+e2+e3);
  if (t < PRED){
    float f = (e0*retr_ws[((size_t)0*BB+b)*PRED+t] + e1*retr_ws[((size_t)1*BB+b)*PRED+t]
             + e2*retr_ws[((size_t)2*BB+b)*PRED+t] + e3*retr_ws[((size_t)3*BB+b)*PRED+t]) * inv;
    size_t base = ((size_t)b*PRED + t)*NCH;
    #pragma unroll
    for (int n=0;n<NCH;n++) out[base+n] = f;
  }
}

extern "C" void kernel_launch(void* const* d_in, const int* in_sizes, int n_in,
                              void* d_out, int out_size, void* d_ws, size_t ws_size,
                              hipStream_t stream)
{
  const float* x          = (const float*)d_in[0];
  const float* keys       = (const float*)d_in[1];
  const float* values     = (const float*)d_in[2];
  const int*   labels     = (const int*)  d_in[3];
  const float* thresholds = (const float*)d_in[4];
  const float* cls_w      = (const float*)d_in[5];
  const float* cls_b      = (const float*)d_in[6];
  const float* prior_mean = (const float*)d_in[7];
  const float* prior_var  = (const float*)d_in[8];
  const float* noise_var  = (const float*)d_in[9];
  const float* enc_W      = (const float*)d_in[10];
  const float* enc_b      = (const float*)d_in[11];
  const float* ln_g       = (const float*)d_in[12];
  const float* ln_b       = (const float*)d_in[13];
  float* out = (float*)d_out;

  float* q_ws     = (float*)d_ws;                                   // S*B*D
  int*   mode_ws  = (int*)(q_ws + (size_t)SS*BB*DD);                // B
  float* cand_val = (float*)(mode_ws + BB);                         // S*NBLK*B*5
  int*   cand_idx = (int*)(cand_val + (size_t)SS*NBLK*BB*5);        // S*NBLK*B*5
  float* top1_ws  = (float*)(cand_idx + (size_t)SS*NBLK*BB*5);      // S*B
  float* retr_ws  = top1_ws + SS*BB;                                // S*B*PRED

  k1_setup<<<dim3(BB), dim3(256), 0, stream>>>(x, cls_w, cls_b, prior_mean,
      prior_var, noise_var, enc_W, enc_b, ln_g, ln_b, q_ws, mode_ws);
  k2_sims<<<dim3(SS*NBLK), dim3(256), 0, stream>>>(keys, labels, q_ws, mode_ws,
      cand_val, cand_idx);
  k3_merge<<<dim3(SS*BB), dim3(256), 0, stream>>>(cand_val, cand_idx, values,
      thresholds, top1_ws, retr_ws, out);
  k4_fuse<<<dim3(BB), dim3(128), 0, stream>>>(top1_ws, retr_ws, out);
}

// Round 2
// 178.781 us; speedup vs baseline: 5.1123x; 1.1092x over previous
//
#include <hip/hip_runtime.h>
#include <math.h>

#define BB   64      // batch
#define TT   512     // time
#define NCH  7       // channels
#define SS   4       // scales
#define MM   100000  // memory entries
#define DD   64      // embed dim
#define PRED 96      // pred_len
#define NBLK 256     // k2 blocks per scale
#define KPB  391     // ceil(MM/NBLK)
#define KPW  98      // ceil(KPB/4) keys per wave

// ---------------- reductions ----------------
__device__ __forceinline__ float wsum(float v){
  v += __shfl_xor(v,32); v += __shfl_xor(v,16); v += __shfl_xor(v,8);
  v += __shfl_xor(v,4);  v += __shfl_xor(v,2);  v += __shfl_xor(v,1);
  return v;
}
__device__ __forceinline__ float wmaxall(float v){
  v = fmaxf(v,__shfl_xor(v,32)); v = fmaxf(v,__shfl_xor(v,16));
  v = fmaxf(v,__shfl_xor(v,8));  v = fmaxf(v,__shfl_xor(v,4));
  v = fmaxf(v,__shfl_xor(v,2));  v = fmaxf(v,__shfl_xor(v,1));
  return v;
}
__device__ __forceinline__ float wminall(float v){
  v = fminf(v,__shfl_xor(v,32)); v = fminf(v,__shfl_xor(v,16));
  v = fminf(v,__shfl_xor(v,8));  v = fminf(v,__shfl_xor(v,4));
  v = fminf(v,__shfl_xor(v,2));  v = fminf(v,__shfl_xor(v,1));
  return v;
}
__device__ __forceinline__ float bsum(float v, float* red, int wid, int lane){
  v = wsum(v);
  __syncthreads();
  if (lane==0) red[wid]=v;
  __syncthreads();
  return (red[0]+red[1])+(red[2]+red[3]);
}
__device__ __forceinline__ float bmax(float v, float* red, int wid, int lane){
  v = wmaxall(v);
  __syncthreads();
  if (lane==0) red[wid]=v;
  __syncthreads();
  return fmaxf(fmaxf(red[0],red[1]),fmaxf(red[2],red[3]));
}
__device__ __forceinline__ float bmin(float v, float* red, int wid, int lane){
  v = wminall(v);
  __syncthreads();
  if (lane==0) red[wid]=v;
  __syncthreads();
  return fminf(fminf(red[0],red[1]),fminf(red[2],red[3]));
}

__device__ __forceinline__ float log_marg(float n, float mean, float var,
                                          float pm, float pv, float nv){
  float post_var = 1.f/(1.f/pv + n/nv);
  float post_mean = post_var*(pm/pv + n*mean/nv);
  return -0.5f*n*logf(6.283185307179586f*nv)
       + 0.5f*logf(post_var/pv)
       - 0.5f*(n*var/nv + mean*mean*n/nv - post_mean*post_mean/post_var + pm*pm/pv);
}

// sorted-desc top5 insert on registers tv0..tv4 / ti0..ti4
#define TOP5_INSERT(v, ii) \
  if ((v) > tv4) { \
    if ((v) > tv0){ tv4=tv3;ti4=ti3;tv3=tv2;ti3=ti2;tv2=tv1;ti2=ti1;tv1=tv0;ti1=ti0;tv0=(v);ti0=(ii);} \
    else if ((v) > tv1){ tv4=tv3;ti4=ti3;tv3=tv2;ti3=ti2;tv2=tv1;ti2=ti1;tv1=(v);ti1=(ii);} \
    else if ((v) > tv2){ tv4=tv3;ti4=ti3;tv3=tv2;ti3=ti2;tv2=(v);ti2=(ii);} \
    else if ((v) > tv3){ tv4=tv3;ti4=ti3;tv3=(v);ti3=(ii);} \
    else { tv4=(v);ti4=(ii);} \
  }

// ---------------- kernel 1: stats + changepoint + mode + encodings ----------------
__global__ __launch_bounds__(256) void k1_setup(
    const float* __restrict__ x,
    const float* __restrict__ cls_w, const float* __restrict__ cls_b,
    const float* __restrict__ prior_mean, const float* __restrict__ prior_var,
    const float* __restrict__ noise_var,
    const float* __restrict__ enc_W, const float* __restrict__ enc_b,
    const float* __restrict__ ln_g, const float* __restrict__ ln_b,
    float* __restrict__ q_ws, int* __restrict__ mode_ws)
{
  __shared__ float xl[TT*NCH];
  __shared__ float xf[TT];
  __shared__ float s1[TT+1];
  __shared__ float s2[TT+1];
  __shared__ float bfl[TT-32];
  __shared__ float xd[TT];
  __shared__ float red[4];
  int b = blockIdx.x, t = threadIdx.x;
  int lane = t & 63, wid = t >> 6;

  for (int i=t; i<TT*NCH; i+=256) xl[i] = x[(size_t)b*TT*NCH + i];
  __syncthreads();
  for (int i=t; i<TT; i+=256){
    float s=0.f;
    #pragma unroll
    for (int n=0;n<NCH;n++) s += xl[i*NCH+n];
    xf[i] = s*(1.0f/NCH);
  }
  __syncthreads();

  // ---- classifier feats (per-channel stats, then mean over channels) ----
  float sum[NCH], ssq[NCH], mxa[NCH], mna[NCH];
  #pragma unroll
  for(int n=0;n<NCH;n++){ sum[n]=0.f; ssq[n]=0.f; mxa[n]=-INFINITY; mna[n]=INFINITY; }
  for (int i=t;i<TT;i+=256){
    #pragma unroll
    for(int n=0;n<NCH;n++){
      float v = xl[i*NCH+n];
      sum[n]+=v; ssq[n]+=v*v; mxa[n]=fmaxf(mxa[n],v); mna[n]=fminf(mna[n],v);
    }
  }
  float f_mean=0.f, f_std=0.f, f_max=0.f, f_min=0.f;
  #pragma unroll
  for(int n=0;n<NCH;n++){
    float sn  = bsum(sum[n], red, wid, lane);
    float qn  = bsum(ssq[n], red, wid, lane);
    float xn  = bmax(mxa[n], red, wid, lane);
    float mn2 = bmin(mna[n], red, wid, lane);
    float m = sn*(1.0f/TT);
    float var = (qn - (float)TT*m*m)*(1.0f/(TT-1));
    f_mean += m; f_std += sqrtf(fmaxf(var, 0.f)); f_max += xn; f_min += mn2;
  }
  f_mean *= (1.0f/NCH); f_std *= (1.0f/NCH); f_max *= (1.0f/NCH); f_min *= (1.0f/NCH);
  f_std = fmaxf(f_std, 1e-6f);
  float trend = 0.f;
  #pragma unroll
  for(int n=0;n<NCH;n++) trend += (xl[(TT-1)*NCH+n]-xl[n]);
  trend *= (1.0f/NCH);
  float z = f_mean*cls_w[0]+f_std*cls_w[1]+f_max*cls_w[2]+f_min*cls_w[3]+trend*cls_w[4]+cls_b[0];
  float extreme_prob = 1.f/(1.f+expf(-z));

  // ---- cumsums (serial, T=512) ----
  if (t==0){
    float a=0.f, c=0.f; s1[0]=0.f; s2[0]=0.f;
    for (int i=0;i<TT;i++){ float v=xf[i]; a+=v; c+=v*v; s1[i+1]=a; s2[i+1]=c; }
  }
  __syncthreads();

  // ---- Bayesian change point ----
  float pm = prior_mean[0];
  float pv = log1pf(expf(prior_var[0]));
  float nv = log1pf(expf(noise_var[0]));
  float sAll = s1[TT], qAll = s2[TT];
  float mw = sAll*(1.0f/TT);
  float vw = fmaxf((qAll - (float)TT*mw*mw)*(1.0f/(TT-1)), 1e-8f);
  float lmw = log_marg((float)TT, mw, vw, pm, pv, nv);
  for (int pp=16+t; pp<TT-16; pp+=256){
    float nl=(float)pp, nr=(float)(TT-pp);
    float ml=s1[pp]/nl;
    float vl=fmaxf((s2[pp]-nl*ml*ml)/(nl-1.f), 1e-8f);
    float sr=sAll-s1[pp], qr=qAll-s2[pp];
    float mr=sr/nr;
    float vr=fmaxf((qr-nr*mr*mr)/(nr-1.f), 1e-8f);
    bfl[pp-16] = log_marg(nl,ml,vl,pm,pv,nv)+log_marg(nr,mr,vr,pm,pv,nv)-lmw;
  }
  __syncthreads();
  float mv = -INFINITY;
  for (int i=t;i<TT-32;i+=256) mv = fmaxf(mv, bfl[i]);
  mv = bmax(mv, red, wid, lane);
  float se=0.f, sme=0.f;
  for (int i=t;i<TT-32;i+=256){
    float e = expf(bfl[i]-mv);
    se += e;
    if (i+16 > 409) sme += e;   // pos > int(512*0.8)=409
  }
  se  = bsum(se,  red, wid, lane);
  sme = bsum(sme, red, wid, lane);
  float near_end = (1.f/(1.f+expf(-mv))) * (sme/se);
  if (t==0) mode_ws[b] = (near_end>0.5f) ? 2 : ((extreme_prob>0.5f) ? 1 : 0);

  // ---- per-scale encodings ----
  for (int si=0; si<SS; si++){
    int ds = 1<<si, Td = TT>>si;
    __syncthreads();
    for (int i=t;i<Td;i+=256)
      xd[i] = (si==0) ? xf[i] : (s1[(i+1)*ds]-s1[i*ds])*(1.0f/(float)ds);
    __syncthreads();
    float s=0.f, qq=0.f, mxv=-INFINITY, mnv=INFINITY;
    for (int i=t;i<Td;i+=256){ float v=xd[i]; s+=v; qq+=v*v; mxv=fmaxf(mxv,v); mnv=fminf(mnv,v); }
    s   = bsum(s,  red, wid, lane);
    qq  = bsum(qq, red, wid, lane);
    mxv = bmax(mxv, red, wid, lane);
    mnv = bmin(mnv, red, wid, lane);
    float m  = s/(float)Td;
    float sd = fmaxf(sqrtf(fmaxf((qq-(float)Td*m*m)/((float)Td-1.f), 0.f)), 1e-6f);
    float tr = xd[Td-1]-xd[0];
    if (t < DD){
      float h = m*enc_W[0*DD+t] + sd*enc_W[1*DD+t] + mxv*enc_W[2*DD+t]
              + mnv*enc_W[3*DD+t] + tr*enc_W[4*DD+t] + enc_b[t];
      float mu  = wsum(h)*(1.0f/DD);
      float dv  = h-mu;
      float var = wsum(dv*dv)*(1.0f/DD);
      float hn  = dv*rsqrtf(var+1e-5f)*ln_g[t] + ln_b[t];
      float nrm2 = wsum(hn*hn);
      q_ws[(((size_t)si*BB)+b)*DD + t] = hn*rsqrtf(nrm2);
    }
  }
}

// ---------------- kernel 2: sims GEMV + per-block top5 ----------------
// Restructure vs previous version (which was LDS-issue bound: 272
// ds_read_b128 per wave per 64-key tile, VALUBusy 49%):
//   lane = batch (64 lanes = 64 batches), wave = contiguous key chunk.
//   q[64] lives in VGPRs per lane (loaded once). Key row address is
//   wave-uniform -> compiler scalarizes to s_load through the constant
//   cache (separate pipe from LDS/VMEM). No LDS, no __syncthreads, no
//   phase B in the main loop; lanes TOP5-insert directly.
__global__ __launch_bounds__(256,4) void k2_sims(
    const float* __restrict__ keys, const int* __restrict__ labels,
    const float* __restrict__ q_ws, const int* __restrict__ mode_ws,
    float* __restrict__ cand_val, int* __restrict__ cand_idx)
{
  __shared__ float mvp[256*5];
  __shared__ int   mip[256*5];
  int bid = blockIdx.x;
  int s   = bid / NBLK, blk = bid % NBLK;
  int t = threadIdx.x, lane = t & 63;
  int w = __builtin_amdgcn_readfirstlane(t >> 6);   // wave id, provably uniform
  int k0   = blk*KPB;
  int kend = min(MM, k0+KPB);
  int kw0  = min(kend, k0 + w*KPW);
  int kw1  = min(kend, kw0 + KPW);
  int mode_l = mode_ws[lane];                        // lane = batch

  // per-lane q (lane = batch): 64 floats in registers, reused for all keys
  float q[DD];
  {
    const float* qp = q_ws + ((size_t)s*BB + lane)*DD;
    #pragma unroll
    for (int d=0; d<DD; d+=4){
      float4 v = *(const float4*)(qp + d);
      q[d]=v.x; q[d+1]=v.y; q[d+2]=v.z; q[d+3]=v.w;
    }
  }

  float tv0=-INFINITY,tv1=-INFINITY,tv2=-INFINITY,tv3=-INFINITY,tv4=-INFINITY;
  int   ti0=0,ti1=0,ti2=0,ti3=0,ti4=0;

  const float* kb = keys + (size_t)s*MM*DD;
  const int*   lbb = labels + (size_t)s*MM;
  for (int m=kw0; m<kw1; ++m){
    const float* kp = kb + (size_t)m*DD;     // wave-uniform -> s_load
    int lb = lbb[m];                         // wave-uniform -> s_load
    float a0=0.f,a1=0.f,a2=0.f,a3=0.f;
    #pragma unroll
    for (int d=0; d<DD; d+=4){
      a0 = fmaf(kp[d  ], q[d  ], a0);
      a1 = fmaf(kp[d+1], q[d+1], a1);
      a2 = fmaf(kp[d+2], q[d+2], a2);
      a3 = fmaf(kp[d+3], q[d+3], a3);
    }
    float v = (a0+a1)+(a2+a3);
    bool allowed = (mode_l==0) | (lb==mode_l);
    if (allowed){
      TOP5_INSERT(v, m)
    }
  }

  // merge 4 wave-lists per batch -> per-block sorted top5
  int slot = (w*64+lane)*5;
  mvp[slot+0]=tv0; mvp[slot+1]=tv1; mvp[slot+2]=tv2; mvp[slot+3]=tv3; mvp[slot+4]=tv4;
  mip[slot+0]=ti0; mip[slot+1]=ti1; mip[slot+2]=ti2; mip[slot+3]=ti3; mip[slot+4]=ti4;
  __syncthreads();
  if (t < 64){
    float tv0=mvp[t*5+0], tv1=mvp[t*5+1], tv2=mvp[t*5+2], tv3=mvp[t*5+3], tv4=mvp[t*5+4];
    int   ti0=mip[t*5+0], ti1=mip[t*5+1], ti2=mip[t*5+2], ti3=mip[t*5+3], ti4=mip[t*5+4];
    #pragma unroll
    for (int ww=1; ww<4; ww++){
      #pragma unroll
      for (int j=0;j<5;j++){
        float v = mvp[(ww*64+t)*5+j]; int ii = mip[(ww*64+t)*5+j];
        TOP5_INSERT(v, ii)
      }
    }
    size_t o = (((size_t)s*NBLK + blk)*BB + t)*5;
    cand_val[o+0]=tv0; cand_val[o+1]=tv1; cand_val[o+2]=tv2; cand_val[o+3]=tv3; cand_val[o+4]=tv4;
    cand_idx[o+0]=ti0; cand_idx[o+1]=ti1; cand_idx[o+2]=ti2; cand_idx[o+3]=ti3; cand_idx[o+4]=ti4;
  }
}

// ---------------- kernel 3: merge candidates, softmax, gather values ----------------
__global__ __launch_bounds__(256) void k3_merge(
    const float* __restrict__ cand_val, const int* __restrict__ cand_idx,
    const float* __restrict__ values, const float* __restrict__ thresholds,
    float* __restrict__ top1_ws, float* __restrict__ retr_ws,
    float* __restrict__ out)
{
  __shared__ float lv[NBLK*5];
  __shared__ int   li[NBLK*5];
  __shared__ float wsm[5];
  __shared__ int   wix[5];
  int bid = blockIdx.x;
  int s = bid >> 6, b = bid & 63;
  int t = threadIdx.x;
  size_t o = (((size_t)s*NBLK + t)*BB + b)*5;
  float tv0=cand_val[o+0], tv1=cand_val[o+1], tv2=cand_val[o+2], tv3=cand_val[o+3], tv4=cand_val[o+4];
  int   ti0=cand_idx[o+0], ti1=cand_idx[o+1], ti2=cand_idx[o+2], ti3=cand_idx[o+3], ti4=cand_idx[o+4];
  lv[t*5+0]=tv0; lv[t*5+1]=tv1; lv[t*5+2]=tv2; lv[t*5+3]=tv3; lv[t*5+4]=tv4;
  li[t*5+0]=ti0; li[t*5+1]=ti1; li[t*5+2]=ti2; li[t*5+3]=ti3; li[t*5+4]=ti4;
  __syncthreads();
  for (int stride=128; stride>=1; stride>>=1){
    if (t < stride){
      int p = t+stride;
      #pragma unroll
      for (int j=0;j<5;j++){
        float v = lv[p*5+j]; int ii = li[p*5+j];
        TOP5_INSERT(v, ii)
      }
      lv[t*5+0]=tv0; lv[t*5+1]=tv1; lv[t*5+2]=tv2; lv[t*5+3]=tv3; lv[t*5+4]=tv4;
      li[t*5+0]=ti0; li[t*5+1]=ti1; li[t*5+2]=ti2; li[t*5+3]=ti3; li[t*5+4]=ti4;
    }
    __syncthreads();
  }
  if (t==0){
    float e1=expf(tv1-tv0), e2=expf(tv2-tv0), e3=expf(tv3-tv0), e4=expf(tv4-tv0);
    float inv = 1.f/(1.f+e1+e2+e3+e4);
    wsm[0]=inv; wsm[1]=e1*inv; wsm[2]=e2*inv; wsm[3]=e3*inv; wsm[4]=e4*inv;
    wix[0]=ti0; wix[1]=ti1; wix[2]=ti2; wix[3]=ti3; wix[4]=ti4;
    top1_ws[s*BB+b] = tv0;
    out[(size_t)BB*PRED*NCH + b*SS + s] = 1.f/(1.f+expf(-(tv0-thresholds[s])));
  }
  __syncthreads();
  if (t < PRED){
    float acc=0.f;
    #pragma unroll
    for (int j=0;j<5;j++)
      acc += wsm[j]*values[((size_t)s*MM + wix[j])*PRED + t];
    retr_ws[((size_t)s*BB + b)*PRED + t] = acc;
  }
}

// ---------------- kernel 4: cross-scale fuse + broadcast over channels ----------------
__global__ __launch_bounds__(128) void k4_fuse(
    const float* __restrict__ top1_ws, const float* __restrict__ retr_ws,
    float* __restrict__ out)
{
  int b = blockIdx.x, t = threadIdx.x;
  float t0=top1_ws[b], t1=top1_ws[BB+b], t2=top1_ws[2*BB+b], t3=top1_ws[3*BB+b];
  float mx = fmaxf(fmaxf(t0,t1),fmaxf(t2,t3));
  float e0=expf(t0-mx), e1=expf(t1-mx), e2=expf(t2-mx), e3=expf(t3-mx);
  float inv = 1.f/(e0+e1+e2+e3);
  if (t < PRED){
    float f = (e0*retr_ws[((size_t)0*BB+b)*PRED+t] + e1*retr_ws[((size_t)1*BB+b)*PRED+t]
             + e2*retr_ws[((size_t)2*BB+b)*PRED+t] + e3*retr_ws[((size_t)3*BB+b)*PRED+t]) * inv;
    size_t base = ((size_t)b*PRED + t)*NCH;
    #pragma unroll
    for (int n=0;n<NCH;n++) out[base+n] = f;
  }
}

extern "C" void kernel_launch(void* const* d_in, const int* in_sizes, int n_in,
                              void* d_out, int out_size, void* d_ws, size_t ws_size,
                              hipStream_t stream)
{
  const float* x          = (const float*)d_in[0];
  const float* keys       = (const float*)d_in[1];
  const float* values     = (const float*)d_in[2];
  const int*   labels     = (const int*)  d_in[3];
  const float* thresholds = (const float*)d_in[4];
  const float* cls_w      = (const float*)d_in[5];
  const float* cls_b      = (const float*)d_in[6];
  const float* prior_mean = (const float*)d_in[7];
  const float* prior_var  = (const float*)d_in[8];
  const float* noise_var  = (const float*)d_in[9];
  const float* enc_W      = (const float*)d_in[10];
  const float* enc_b      = (const float*)d_in[11];
  const float* ln_g       = (const float*)d_in[12];
  const float* ln_b       = (const float*)d_in[13];
  float* out = (float*)d_out;

  float* q_ws     = (float*)d_ws;                                   // S*B*D
  int*   mode_ws  = (int*)(q_ws + (size_t)SS*BB*DD);                // B
  float* cand_val = (float*)(mode_ws + BB);                         // S*NBLK*B*5
  int*   cand_idx = (int*)(cand_val + (size_t)SS*NBLK*BB*5);        // S*NBLK*B*5
  float* top1_ws  = (float*)(cand_idx + (size_t)SS*NBLK*BB*5);      // S*B
  float* retr_ws  = top1_ws + SS*BB;                                // S*B*PRED

  k1_setup<<<dim3(BB), dim3(256), 0, stream>>>(x, cls_w, cls_b, prior_mean,
      prior_var, noise_var, enc_W, enc_b, ln_g, ln_b, q_ws, mode_ws);
  k2_sims<<<dim3(SS*NBLK), dim3(256), 0, stream>>>(keys, labels, q_ws, mode_ws,
      cand_val, cand_idx);
  k3_merge<<<dim3(SS*BB), dim3(256), 0, stream>>>(cand_val, cand_idx, values,
      thresholds, top1_ws, retr_ws, out);
  k4_fuse<<<dim3(BB), dim3(128), 0, stream>>>(top1_ws, retr_ws, out);
}